// Round 4
// baseline (284.840 us; speedup 1.0000x reference)
//
#include <hip/hip_runtime.h>
#include <stdint.h>

#define BB 16
#define TT 4096
#define CC 8
#define FF 64
#define KW 11
#define LL 4096

#define L2E 1.442695040888963f

typedef __attribute__((ext_vector_type(8))) short short8;
typedef __attribute__((ext_vector_type(16))) float floatx16;

__device__ __forceinline__ unsigned short f2b(float f) {
    union { float f; uint32_t i; } v; v.f = f;
    uint32_t x = v.i;
    return (unsigned short)((x + 0x7fffu + ((x >> 16) & 1u)) >> 16);  // RNE
}
__device__ __forceinline__ float b2f(unsigned short u) {
    union { uint32_t i; float f; } v; v.i = ((uint32_t)u) << 16; return v.f;
}

// ---------------- Kernel 0: W fp32 [64][4096] -> Whi / Wlo bf16 planes,
// fragment-linear order [ltile 128][kf 4][half 2][ln 32][j 8].
__global__ __launch_bounds__(256) void k_split(
        const float* __restrict__ dw, unsigned short* __restrict__ Wt) {
    const int idx  = blockIdx.x * 256 + threadIdx.x;   // 262144
    const int j    = idx & 7;
    const int ln   = (idx >> 3) & 31;
    const int half = (idx >> 8) & 1;
    const int kf   = (idx >> 9) & 3;
    const int lt   = idx >> 11;
    const int l = lt * 32 + ln;
    const int k = kf * 16 + half * 8 + j;
    const float v = dw[(size_t)k * LL + l];
    const unsigned short hi = f2b(v);
    const unsigned short lo = f2b(v - b2f(hi));
    Wt[idx] = hi;
    Wt[262144 + idx] = lo;
}

// ---------------- Kernel 1: conv1d + BN + exp -> sumexp[b,f] ----------------------
__global__ __launch_bounds__(256) void k_sumexp(
        const float* __restrict__ x, const float* __restrict__ cw,
        const float* __restrict__ cb, const float* __restrict__ gm,
        const float* __restrict__ bt, const float* __restrict__ mn,
        const float* __restrict__ vr, float* __restrict__ sumexp) {
    __shared__ __align__(16) float xsm[(64 + KW - 1) * CC];   // 592 floats
    __shared__ float red[4 * FF];
    const int tid = threadIdx.x;
    const int b  = blockIdx.x / (TT / 64);
    const int t0 = (blockIdx.x % (TT / 64)) * 64;
    const int f = tid & 63, ts = tid >> 6;

    float wreg[KW * CC];
#pragma unroll
    for (int kc = 0; kc < KW * CC; ++kc) wreg[kc] = cw[kc * FF + f];

    for (int i = tid; i < (64 + KW - 1) * CC; i += 256) {
        int row = i >> 3, c = i & 7;
        int t = t0 - (KW / 2) + row;
        xsm[i] = (t >= 0 && t < TT) ? x[((size_t)b * TT + t) * CC + c] : 0.0f;
    }
    const float s  = gm[f] * rsqrtf(vr[f] + 1e-3f);
    const float bb = bt[f] + (cb[f] - mn[f]) * s;
    const float s2 = s * L2E, b2 = bb * L2E;   // exp(z) = exp2(z*log2e), fold
    __syncthreads();

    const float4* xv = (const float4*)xsm;
    float esum = 0.f;
#pragma unroll 2
    for (int i = 0; i < 16; ++i) {
        const int tt = ts + 4 * i;
        float acc = 0.f;
#pragma unroll
        for (int k = 0; k < KW; ++k) {
            const float4 xa = xv[(tt + k) * 2];
            const float4 xb = xv[(tt + k) * 2 + 1];
            acc = fmaf(xa.x, wreg[k * 8 + 0], acc);
            acc = fmaf(xa.y, wreg[k * 8 + 1], acc);
            acc = fmaf(xa.z, wreg[k * 8 + 2], acc);
            acc = fmaf(xa.w, wreg[k * 8 + 3], acc);
            acc = fmaf(xb.x, wreg[k * 8 + 4], acc);
            acc = fmaf(xb.y, wreg[k * 8 + 5], acc);
            acc = fmaf(xb.z, wreg[k * 8 + 6], acc);
            acc = fmaf(xb.w, wreg[k * 8 + 7], acc);
        }
        esum += __builtin_amdgcn_exp2f(fmaf(acc, s2, b2));
    }
    red[ts * FF + f] = esum;
    __syncthreads();
    if (ts == 0) {
        float tot = red[f] + red[FF + f] + red[2 * FF + f] + red[3 * FF + f];
        atomicAdd(&sumexp[b * FF + f], tot);
    }
}

// ---------------- Kernel 2: conv+softmax+pos -> pre-split bf16 planes in LDS,
// swapped-operand MFMA (A = h over t, B = W over l). 512 threads = 8 waves:
// 2 blocks/CU -> 16 waves/CU = 4 waves/SIMD (VGPR<=128 pinned by launch_bounds).
// Sigmoid epilogue: 4-way reciprocal batching (1 rcp per 4 values) + exp2-folded
// args. Pos encoding via 1 precise sincos + rotation recurrence (no libm in loop).
__global__ __launch_bounds__(512, 4) void k_main(
        const float* __restrict__ x,  const float* __restrict__ cw,
        const float* __restrict__ cb, const float* __restrict__ gm,
        const float* __restrict__ bt, const float* __restrict__ mn,
        const float* __restrict__ vr, const unsigned short* __restrict__ Wt,
        const float* __restrict__ db, const float* __restrict__ sumexp,
        float* __restrict__ shiftsum) {
    __shared__ __align__(16) unsigned short As[16384];           // 32 KB: hi | lo planes
    __shared__ __align__(16) float xsm[(128 + KW - 1) * CC];     // 4416 B, disjoint

    const int tid = threadIdx.x;
    const int b  = blockIdx.y;
    const int t0 = blockIdx.x * 128;
    const int f = tid & 63, tq = tid >> 6;   // tq in 0..7

    // conv weights for this thread's f: 88 registers (dead before the main loop)
    float wreg[KW * CC];
#pragma unroll
    for (int kc = 0; kc < KW * CC; ++kc) wreg[kc] = cw[kc * FF + f];

    for (int i = tid; i < (128 + KW - 1) * CC; i += 512) {
        int row = i >> 3, c = i & 7;
        int t = t0 - (KW / 2) + row;
        xsm[i] = (t >= 0 && t < TT) ? x[((size_t)b * TT + t) * CC + c] : 0.0f;
    }
    const float s   = gm[f] * rsqrtf(vr[f] + 1e-3f);
    const float bbv = bt[f] + (cb[f] - mn[f]) * s;
    const float s2 = s * L2E, b2 = bbv * L2E;
    const float inv_se = 1.0f / sumexp[b * FF + f];
    const float tsf = exp2f(-0.20762050586796017f * (float)(f & ~1));
    const int kfh = ((f >> 4) << 1) | ((f >> 3) & 1);   // kf*2 + half
    const int jj  = f & 7;
    // pos encoding: ang(t) = t*tsf; this thread visits t = t0+tq+8*i.
    // One precise sincos, then rotate by dA = 8*tsf per step (drift ~2e-6).
    const float ang0 = (float)(t0 + tq) * tsf;
    const float dA = 8.0f * tsf;
    float sv = sinf(ang0), cv = cosf(ang0);
    const float sd = sinf(dA), cd = cosf(dA);
    __syncthreads();

    // conv + BN + softmax + pos -> split hi/lo -> As, 16 t per thread
    const float4* xv = (const float4*)xsm;
#pragma unroll 2
    for (int i = 0; i < 16; ++i) {
        const int tt = tq + 8 * i;
        float acc = 0.f;
#pragma unroll
        for (int k = 0; k < KW; ++k) {
            const float4 xa = xv[(tt + k) * 2];
            const float4 xb = xv[(tt + k) * 2 + 1];
            acc = fmaf(xa.x, wreg[k * 8 + 0], acc);
            acc = fmaf(xa.y, wreg[k * 8 + 1], acc);
            acc = fmaf(xa.z, wreg[k * 8 + 2], acc);
            acc = fmaf(xa.w, wreg[k * 8 + 3], acc);
            acc = fmaf(xb.x, wreg[k * 8 + 4], acc);
            acc = fmaf(xb.y, wreg[k * 8 + 5], acc);
            acc = fmaf(xb.z, wreg[k * 8 + 6], acc);
            acc = fmaf(xb.w, wreg[k * 8 + 7], acc);
        }
        float e = __builtin_amdgcn_exp2f(fmaf(acc, s2, b2));
        float p = (f & 1) ? cv : sv;
        float h = fmaf(e, inv_se, p);
        const unsigned short hi = f2b(h);
        const unsigned short lo = f2b(h - b2f(hi));
        const int off = ((tt >> 5) * 8 + kfh) * 256 + (tt & 31) * 8 + jj;
        As[off] = hi;
        As[8192 + off] = lo;
        // rotate (sv,cv) by dA
        float ns = fmaf(sv, cd, cv * sd);
        float nc = fmaf(cv, cd, -(sv * sd));
        sv = ns; cv = nc;
    }
    __syncthreads();

    // ---- main loop: A frags re-read from LDS each lt (keeps VGPR<=128 ->
    // 4 waves/SIMD; the compiler chose this over a 128-reg hoist in R3) ----
    const int lane = tid & 63;
    const int wv   = tid >> 6;            // 0..7
    const int half = lane >> 5;
    const int ln31 = lane & 31;
    const int vbase = (half << 9) | (ln31 << 4);            // byte offset of lane
    const char* Ab = (const char*)As;
    const char* Wb = (const char*)Wt;

#pragma unroll 1
    for (int lt = 0; lt < 16; ++lt) {
        const int ltile = lt * 8 + wv;    // 8 waves cover 128 ltiles
        const int lbase = ltile * 32;
        const char* wp = Wb + ((size_t)ltile << 12) + vbase;
        short8 Whi[4], Wlo[4];
#pragma unroll
        for (int kf = 0; kf < 4; ++kf) {
            Whi[kf] = *reinterpret_cast<const short8*>(wp + kf * 1024);
            Wlo[kf] = *reinterpret_cast<const short8*>(wp + 524288 + kf * 1024);
        }
        const float dbn = db[lbase + ln31] * (-L2E);   // exp(-z) = exp2(-z*log2e)

        float ss[4] = {0.f, 0.f, 0.f, 0.f};
#pragma unroll
        for (int nt = 0; nt < 4; ++nt) {
            floatx16 acc = {0.f, 0.f, 0.f, 0.f, 0.f, 0.f, 0.f, 0.f,
                            0.f, 0.f, 0.f, 0.f, 0.f, 0.f, 0.f, 0.f};
#pragma unroll
            for (int kf = 0; kf < 4; ++kf) {
                const int ao = (nt * 8 + kf * 2) << 9;
                short8 Ahi = *reinterpret_cast<const short8*>(Ab + ao + vbase);
                short8 Alo = *reinterpret_cast<const short8*>(Ab + 16384 + ao + vbase);
                acc = __builtin_amdgcn_mfma_f32_32x32x16_bf16(Ahi, Whi[kf], acc, 0, 0, 0);
                acc = __builtin_amdgcn_mfma_f32_32x32x16_bf16(Alo, Whi[kf], acc, 0, 0, 0);
                acc = __builtin_amdgcn_mfma_f32_32x32x16_bf16(Ahi, Wlo[kf], acc, 0, 0, 0);
            }
            // sum of 16 sigmoids, 4-way reciprocal batching:
            // 1/a0+1/a1+1/a2+1/a3 = ((a0+a1)*a2*a3 + (a2+a3)*a0*a1) / (a0*a1*a2*a3)
#pragma unroll
            for (int q = 0; q < 4; ++q) {
                float e0 = __builtin_amdgcn_exp2f(fmaf(acc[4 * q + 0], -L2E, dbn));
                float e1 = __builtin_amdgcn_exp2f(fmaf(acc[4 * q + 1], -L2E, dbn));
                float e2 = __builtin_amdgcn_exp2f(fmaf(acc[4 * q + 2], -L2E, dbn));
                float e3 = __builtin_amdgcn_exp2f(fmaf(acc[4 * q + 3], -L2E, dbn));
                float a0 = 1.f + e0, a1 = 1.f + e1, a2 = 1.f + e2, a3 = 1.f + e3;
                float p01 = a0 * a1, p23 = a2 * a3;
                float num = fmaf(a0 + a1, p23, (a2 + a3) * p01);
                ss[q] = fmaf(num, __builtin_amdgcn_rcpf(p01 * p23), ss[q]);
            }
        }
        float ssum = (ss[0] + ss[1]) + (ss[2] + ss[3]);
        ssum += __shfl_xor(ssum, 32);
        if (half == 0)
            atomicAdd(shiftsum + (size_t)b * LL + lbase + ln31, ssum);
    }
}

// ---------------- Kernel 3: truncated Gaussian warp (shift = 2*S - T) -------------
__global__ __launch_bounds__(256) void k_warp(
        const float* __restrict__ shiftsum, const float* __restrict__ x,
        float* __restrict__ out) {
    const int idx = blockIdx.x * 256 + threadIdx.x;  // = b*L + l
    const int l = idx & (LL - 1);
    const int b = idx >> 12;
    const float sh = fmaf(2.0f, shiftsum[idx], -(float)TT);
    const float scale = (float)TT / (float)LL;
    const float center = ((float)(l + 1) + sh) * scale;
    const float R = 7.0f;
    int tlo = (int)ceilf(center - 1.0f - R);
    int thi = (int)floorf(center - 1.0f + R);
    if (tlo < 0) tlo = 0;
    if (thi > TT - 1) thi = TT - 1;
    float acc[CC];
#pragma unroll
    for (int c = 0; c < CC; ++c) acc[c] = 0.f;
    const float inv_amp = (float)(1.0 / 1.772637204826652);
    for (int t = tlo; t <= thi; ++t) {
        float d = (float)(t + 1) - center;
        float w = __expf(-d * d) * inv_amp;   // WIDTH = 1
        const float4 x0 = *reinterpret_cast<const float4*>(x + ((size_t)b * TT + t) * CC);
        const float4 x1 = *reinterpret_cast<const float4*>(x + ((size_t)b * TT + t) * CC + 4);
        acc[0] = fmaf(w, x0.x, acc[0]);
        acc[1] = fmaf(w, x0.y, acc[1]);
        acc[2] = fmaf(w, x0.z, acc[2]);
        acc[3] = fmaf(w, x0.w, acc[3]);
        acc[4] = fmaf(w, x1.x, acc[4]);
        acc[5] = fmaf(w, x1.y, acc[5]);
        acc[6] = fmaf(w, x1.z, acc[6]);
        acc[7] = fmaf(w, x1.w, acc[7]);
    }
    float* o = out + (size_t)idx * CC;
    *reinterpret_cast<float4*>(o)     = make_float4(acc[0], acc[1], acc[2], acc[3]);
    *reinterpret_cast<float4*>(o + 4) = make_float4(acc[4], acc[5], acc[6], acc[7]);
}

extern "C" void kernel_launch(void* const* d_in, const int* in_sizes, int n_in,
                              void* d_out, int out_size, void* d_ws, size_t ws_size,
                              hipStream_t stream) {
    const float* x  = (const float*)d_in[0];
    const float* cw = (const float*)d_in[1];
    const float* cb = (const float*)d_in[2];
    const float* gm = (const float*)d_in[3];
    const float* bt = (const float*)d_in[4];
    const float* mn = (const float*)d_in[5];
    const float* vr = (const float*)d_in[6];
    const float* dw = (const float*)d_in[7];
    const float* db = (const float*)d_in[8];

    float* sumexp      = (float*)d_ws;                        // 1024 floats
    float* shiftsum    = sumexp + BB * FF;                    // 65536 floats
    unsigned short* Wt = (unsigned short*)(shiftsum + BB * LL); // 524288 ushorts (1 MB)

    hipMemsetAsync(sumexp, 0, (size_t)(BB * FF + BB * LL) * sizeof(float), stream);

    k_split<<<(FF * LL) / 256, 256, 0, stream>>>(dw, Wt);
    k_sumexp<<<BB * (TT / 64), 256, 0, stream>>>(x, cw, cb, gm, bt, mn, vr, sumexp);
    k_main<<<dim3(TT / 128, BB), 512, 0, stream>>>(x, cw, cb, gm, bt, mn, vr,
                                                   Wt, db, sumexp, shiftsum);
    k_warp<<<(BB * LL) / 256, 256, 0, stream>>>(shiftsum, x, (float*)d_out);
}

// Round 5
// 217.791 us; speedup vs baseline: 1.3079x; 1.3079x over previous
//
#include <hip/hip_runtime.h>
#include <stdint.h>

#define BB 16
#define TT 4096
#define CC 8
#define FF 64
#define KW 11
#define LL 4096

#define L2E 1.442695040888963f

typedef __attribute__((ext_vector_type(8))) short short8;
typedef __attribute__((ext_vector_type(16))) float floatx16;

__device__ __forceinline__ unsigned short f2b(float f) {
    union { float f; uint32_t i; } v; v.f = f;
    uint32_t x = v.i;
    return (unsigned short)((x + 0x7fffu + ((x >> 16) & 1u)) >> 16);  // RNE
}
__device__ __forceinline__ float b2f(unsigned short u) {
    union { uint32_t i; float f; } v; v.i = ((uint32_t)u) << 16; return v.f;
}

// ---------------- Kernel 0: W fp32 [64][4096] -> Whi / Wlo bf16 planes,
// fragment-linear order [ltile 128][kf 4][half 2][ln 32][j 8].
__global__ __launch_bounds__(256) void k_split(
        const float* __restrict__ dw, unsigned short* __restrict__ Wt) {
    const int idx  = blockIdx.x * 256 + threadIdx.x;   // 262144
    const int j    = idx & 7;
    const int ln   = (idx >> 3) & 31;
    const int half = (idx >> 8) & 1;
    const int kf   = (idx >> 9) & 3;
    const int lt   = idx >> 11;
    const int l = lt * 32 + ln;
    const int k = kf * 16 + half * 8 + j;
    const float v = dw[(size_t)k * LL + l];
    const unsigned short hi = f2b(v);
    const unsigned short lo = f2b(v - b2f(hi));
    Wt[idx] = hi;
    Wt[262144 + idx] = lo;
}

// ---------------- Kernel 1: conv1d + BN + exp -> sumexp[b,f] ----------------------
__global__ __launch_bounds__(256) void k_sumexp(
        const float* __restrict__ x, const float* __restrict__ cw,
        const float* __restrict__ cb, const float* __restrict__ gm,
        const float* __restrict__ bt, const float* __restrict__ mn,
        const float* __restrict__ vr, float* __restrict__ sumexp) {
    __shared__ __align__(16) float xsm[(64 + KW - 1) * CC];   // 592 floats
    __shared__ float red[4 * FF];
    const int tid = threadIdx.x;
    const int b  = blockIdx.x / (TT / 64);
    const int t0 = (blockIdx.x % (TT / 64)) * 64;
    const int f = tid & 63, ts = tid >> 6;

    float wreg[KW * CC];
#pragma unroll
    for (int kc = 0; kc < KW * CC; ++kc) wreg[kc] = cw[kc * FF + f];

    for (int i = tid; i < (64 + KW - 1) * CC; i += 256) {
        int row = i >> 3, c = i & 7;
        int t = t0 - (KW / 2) + row;
        xsm[i] = (t >= 0 && t < TT) ? x[((size_t)b * TT + t) * CC + c] : 0.0f;
    }
    const float s  = gm[f] * rsqrtf(vr[f] + 1e-3f);
    const float bb = bt[f] + (cb[f] - mn[f]) * s;
    const float s2 = s * L2E, b2 = bb * L2E;   // exp(z) = exp2(z*log2e), fold
    __syncthreads();

    const float4* xv = (const float4*)xsm;
    float esum = 0.f;
#pragma unroll 2
    for (int i = 0; i < 16; ++i) {
        const int tt = ts + 4 * i;
        float acc = 0.f;
#pragma unroll
        for (int k = 0; k < KW; ++k) {
            const float4 xa = xv[(tt + k) * 2];
            const float4 xb = xv[(tt + k) * 2 + 1];
            acc = fmaf(xa.x, wreg[k * 8 + 0], acc);
            acc = fmaf(xa.y, wreg[k * 8 + 1], acc);
            acc = fmaf(xa.z, wreg[k * 8 + 2], acc);
            acc = fmaf(xa.w, wreg[k * 8 + 3], acc);
            acc = fmaf(xb.x, wreg[k * 8 + 4], acc);
            acc = fmaf(xb.y, wreg[k * 8 + 5], acc);
            acc = fmaf(xb.z, wreg[k * 8 + 6], acc);
            acc = fmaf(xb.w, wreg[k * 8 + 7], acc);
        }
        esum += __builtin_amdgcn_exp2f(fmaf(acc, s2, b2));
    }
    red[ts * FF + f] = esum;
    __syncthreads();
    if (ts == 0) {
        float tot = red[f] + red[FF + f] + red[2 * FF + f] + red[3 * FF + f];
        atomicAdd(&sumexp[b * FF + f], tot);
    }
}

// ---------------- Kernel 2: conv+softmax+pos -> pre-split bf16 planes in LDS,
// swapped-operand MFMA (A = h over t, B = W over l). 512 threads = 8 waves:
// 2 blocks/CU -> 16 waves/CU = 4 waves/SIMD, provided VGPR<=128 (natural demand
// was 124 in R3). PLAIN __launch_bounds__ — the min-waves arg clamps VGPR to 64
// and spills hundreds of MB (measured R1: (256,4)->64, R4: (512,4)->64).
__global__ __launch_bounds__(512) void k_main(
        const float* __restrict__ x,  const float* __restrict__ cw,
        const float* __restrict__ cb, const float* __restrict__ gm,
        const float* __restrict__ bt, const float* __restrict__ mn,
        const float* __restrict__ vr, const unsigned short* __restrict__ Wt,
        const float* __restrict__ db, const float* __restrict__ sumexp,
        float* __restrict__ shiftsum) {
    __shared__ __align__(16) unsigned short As[16384];           // 32 KB: hi | lo planes
    __shared__ __align__(16) float xsm[(128 + KW - 1) * CC];     // 4416 B, disjoint

    const int tid = threadIdx.x;
    const int b  = blockIdx.y;
    const int t0 = blockIdx.x * 128;
    const int f = tid & 63, tq = tid >> 6;   // tq in 0..7

    // conv weights for this thread's f: 88 registers (dead before the main loop)
    float wreg[KW * CC];
#pragma unroll
    for (int kc = 0; kc < KW * CC; ++kc) wreg[kc] = cw[kc * FF + f];

    for (int i = tid; i < (128 + KW - 1) * CC; i += 512) {
        int row = i >> 3, c = i & 7;
        int t = t0 - (KW / 2) + row;
        xsm[i] = (t >= 0 && t < TT) ? x[((size_t)b * TT + t) * CC + c] : 0.0f;
    }
    const float s   = gm[f] * rsqrtf(vr[f] + 1e-3f);
    const float bbv = bt[f] + (cb[f] - mn[f]) * s;
    const float s2 = s * L2E, b2 = bbv * L2E;
    const float inv_se = 1.0f / sumexp[b * FF + f];
    const float tsf = exp2f(-0.20762050586796017f * (float)(f & ~1));
    const int kfh = ((f >> 4) << 1) | ((f >> 3) & 1);   // kf*2 + half
    const int jj  = f & 7;
    // pos encoding: ang(t) = t*tsf; this thread visits t = t0+tq+8*i.
    // One precise sincos, then rotate by dA = 8*tsf per step (drift ~2e-6).
    const float ang0 = (float)(t0 + tq) * tsf;
    const float dA = 8.0f * tsf;
    float sv = sinf(ang0), cv = cosf(ang0);
    const float sd = sinf(dA), cd = cosf(dA);
    __syncthreads();

    // conv + BN + softmax + pos -> split hi/lo -> As, 16 t per thread
    const float4* xv = (const float4*)xsm;
#pragma unroll 2
    for (int i = 0; i < 16; ++i) {
        const int tt = tq + 8 * i;
        float acc = 0.f;
#pragma unroll
        for (int k = 0; k < KW; ++k) {
            const float4 xa = xv[(tt + k) * 2];
            const float4 xb = xv[(tt + k) * 2 + 1];
            acc = fmaf(xa.x, wreg[k * 8 + 0], acc);
            acc = fmaf(xa.y, wreg[k * 8 + 1], acc);
            acc = fmaf(xa.z, wreg[k * 8 + 2], acc);
            acc = fmaf(xa.w, wreg[k * 8 + 3], acc);
            acc = fmaf(xb.x, wreg[k * 8 + 4], acc);
            acc = fmaf(xb.y, wreg[k * 8 + 5], acc);
            acc = fmaf(xb.z, wreg[k * 8 + 6], acc);
            acc = fmaf(xb.w, wreg[k * 8 + 7], acc);
        }
        float e = __builtin_amdgcn_exp2f(fmaf(acc, s2, b2));
        float p = (f & 1) ? cv : sv;
        float h = fmaf(e, inv_se, p);
        const unsigned short hi = f2b(h);
        const unsigned short lo = f2b(h - b2f(hi));
        const int off = ((tt >> 5) * 8 + kfh) * 256 + (tt & 31) * 8 + jj;
        As[off] = hi;
        As[8192 + off] = lo;
        // rotate (sv,cv) by dA
        float ns = fmaf(sv, cd, cv * sd);
        float nc = fmaf(cv, cd, -(sv * sd));
        sv = ns; cv = nc;
    }
    __syncthreads();

    // ---- main loop: A frags re-read from LDS each lt (keeps VGPR<=128) ----
    const int lane = tid & 63;
    const int wv   = tid >> 6;            // 0..7
    const int half = lane >> 5;
    const int ln31 = lane & 31;
    const int vbase = (half << 9) | (ln31 << 4);            // byte offset of lane
    const char* Ab = (const char*)As;
    const char* Wb = (const char*)Wt;

#pragma unroll 1
    for (int lt = 0; lt < 16; ++lt) {
        const int ltile = lt * 8 + wv;    // 8 waves cover 128 ltiles
        const int lbase = ltile * 32;
        const char* wp = Wb + ((size_t)ltile << 12) + vbase;
        short8 Whi[4], Wlo[4];
#pragma unroll
        for (int kf = 0; kf < 4; ++kf) {
            Whi[kf] = *reinterpret_cast<const short8*>(wp + kf * 1024);
            Wlo[kf] = *reinterpret_cast<const short8*>(wp + 524288 + kf * 1024);
        }
        const float dbn = db[lbase + ln31] * (-L2E);   // exp(-z) = exp2(-z*log2e)

        float ss[4] = {0.f, 0.f, 0.f, 0.f};
#pragma unroll
        for (int nt = 0; nt < 4; ++nt) {
            floatx16 acc = {0.f, 0.f, 0.f, 0.f, 0.f, 0.f, 0.f, 0.f,
                            0.f, 0.f, 0.f, 0.f, 0.f, 0.f, 0.f, 0.f};
#pragma unroll
            for (int kf = 0; kf < 4; ++kf) {
                const int ao = (nt * 8 + kf * 2) << 9;
                short8 Ahi = *reinterpret_cast<const short8*>(Ab + ao + vbase);
                short8 Alo = *reinterpret_cast<const short8*>(Ab + 16384 + ao + vbase);
                acc = __builtin_amdgcn_mfma_f32_32x32x16_bf16(Ahi, Whi[kf], acc, 0, 0, 0);
                acc = __builtin_amdgcn_mfma_f32_32x32x16_bf16(Alo, Whi[kf], acc, 0, 0, 0);
                acc = __builtin_amdgcn_mfma_f32_32x32x16_bf16(Ahi, Wlo[kf], acc, 0, 0, 0);
            }
            // sum of 16 sigmoids, 4-way reciprocal batching:
            // 1/a0+1/a1+1/a2+1/a3 = ((a0+a1)*a2*a3 + (a2+a3)*a0*a1) / (a0*a1*a2*a3)
#pragma unroll
            for (int q = 0; q < 4; ++q) {
                float e0 = __builtin_amdgcn_exp2f(fmaf(acc[4 * q + 0], -L2E, dbn));
                float e1 = __builtin_amdgcn_exp2f(fmaf(acc[4 * q + 1], -L2E, dbn));
                float e2 = __builtin_amdgcn_exp2f(fmaf(acc[4 * q + 2], -L2E, dbn));
                float e3 = __builtin_amdgcn_exp2f(fmaf(acc[4 * q + 3], -L2E, dbn));
                float a0 = 1.f + e0, a1 = 1.f + e1, a2 = 1.f + e2, a3 = 1.f + e3;
                float p01 = a0 * a1, p23 = a2 * a3;
                float num = fmaf(a0 + a1, p23, (a2 + a3) * p01);
                ss[q] = fmaf(num, __builtin_amdgcn_rcpf(p01 * p23), ss[q]);
            }
        }
        float ssum = (ss[0] + ss[1]) + (ss[2] + ss[3]);
        ssum += __shfl_xor(ssum, 32);
        if (half == 0)
            atomicAdd(shiftsum + (size_t)b * LL + lbase + ln31, ssum);
    }
}

// ---------------- Kernel 3: truncated Gaussian warp (shift = 2*S - T) -------------
__global__ __launch_bounds__(256) void k_warp(
        const float* __restrict__ shiftsum, const float* __restrict__ x,
        float* __restrict__ out) {
    const int idx = blockIdx.x * 256 + threadIdx.x;  // = b*L + l
    const int l = idx & (LL - 1);
    const int b = idx >> 12;
    const float sh = fmaf(2.0f, shiftsum[idx], -(float)TT);
    const float scale = (float)TT / (float)LL;
    const float center = ((float)(l + 1) + sh) * scale;
    const float R = 7.0f;
    int tlo = (int)ceilf(center - 1.0f - R);
    int thi = (int)floorf(center - 1.0f + R);
    if (tlo < 0) tlo = 0;
    if (thi > TT - 1) thi = TT - 1;
    float acc[CC];
#pragma unroll
    for (int c = 0; c < CC; ++c) acc[c] = 0.f;
    const float inv_amp = (float)(1.0 / 1.772637204826652);
    for (int t = tlo; t <= thi; ++t) {
        float d = (float)(t + 1) - center;
        float w = __expf(-d * d) * inv_amp;   // WIDTH = 1
        const float4 x0 = *reinterpret_cast<const float4*>(x + ((size_t)b * TT + t) * CC);
        const float4 x1 = *reinterpret_cast<const float4*>(x + ((size_t)b * TT + t) * CC + 4);
        acc[0] = fmaf(w, x0.x, acc[0]);
        acc[1] = fmaf(w, x0.y, acc[1]);
        acc[2] = fmaf(w, x0.z, acc[2]);
        acc[3] = fmaf(w, x0.w, acc[3]);
        acc[4] = fmaf(w, x1.x, acc[4]);
        acc[5] = fmaf(w, x1.y, acc[5]);
        acc[6] = fmaf(w, x1.z, acc[6]);
        acc[7] = fmaf(w, x1.w, acc[7]);
    }
    float* o = out + (size_t)idx * CC;
    *reinterpret_cast<float4*>(o)     = make_float4(acc[0], acc[1], acc[2], acc[3]);
    *reinterpret_cast<float4*>(o + 4) = make_float4(acc[4], acc[5], acc[6], acc[7]);
}

extern "C" void kernel_launch(void* const* d_in, const int* in_sizes, int n_in,
                              void* d_out, int out_size, void* d_ws, size_t ws_size,
                              hipStream_t stream) {
    const float* x  = (const float*)d_in[0];
    const float* cw = (const float*)d_in[1];
    const float* cb = (const float*)d_in[2];
    const float* gm = (const float*)d_in[3];
    const float* bt = (const float*)d_in[4];
    const float* mn = (const float*)d_in[5];
    const float* vr = (const float*)d_in[6];
    const float* dw = (const float*)d_in[7];
    const float* db = (const float*)d_in[8];

    float* sumexp      = (float*)d_ws;                        // 1024 floats
    float* shiftsum    = sumexp + BB * FF;                    // 65536 floats
    unsigned short* Wt = (unsigned short*)(shiftsum + BB * LL); // 524288 ushorts (1 MB)

    hipMemsetAsync(sumexp, 0, (size_t)(BB * FF + BB * LL) * sizeof(float), stream);

    k_split<<<(FF * LL) / 256, 256, 0, stream>>>(dw, Wt);
    k_sumexp<<<BB * (TT / 64), 256, 0, stream>>>(x, cw, cb, gm, bt, mn, vr, sumexp);
    k_main<<<dim3(TT / 128, BB), 512, 0, stream>>>(x, cw, cb, gm, bt, mn, vr,
                                                   Wt, db, sumexp, shiftsum);
    k_warp<<<(BB * LL) / 256, 256, 0, stream>>>(shiftsum, x, (float*)d_out);
}

// Round 6
// 206.304 us; speedup vs baseline: 1.3807x; 1.0557x over previous
//
#include <hip/hip_runtime.h>
#include <stdint.h>

#define BB 16
#define TT 4096
#define CC 8
#define FF 64
#define KW 11
#define LL 4096

#define L2E 1.442695040888963f

typedef __attribute__((ext_vector_type(8))) short short8;
typedef __attribute__((ext_vector_type(16))) float floatx16;

// exp(conv+BN) staging buffer — device global (d_ws capacity unknown; 16.8 MB)
__device__ float e_buf[(size_t)BB * TT * FF];

__device__ __forceinline__ unsigned short f2b(float f) {
    union { float f; uint32_t i; } v; v.f = f;
    uint32_t x = v.i;
    return (unsigned short)((x + 0x7fffu + ((x >> 16) & 1u)) >> 16);  // RNE
}
__device__ __forceinline__ float b2f(unsigned short u) {
    union { uint32_t i; float f; } v; v.i = ((uint32_t)u) << 16; return v.f;
}

// ---------------- Kernel 0: W fp32 [64][4096] -> Whi / Wlo bf16 planes,
// fragment-linear order [ltile 128][kf 4][half 2][ln 32][j 8].
__global__ __launch_bounds__(256) void k_split(
        const float* __restrict__ dw, unsigned short* __restrict__ Wt) {
    const int idx  = blockIdx.x * 256 + threadIdx.x;   // 262144
    const int j    = idx & 7;
    const int ln   = (idx >> 3) & 31;
    const int half = (idx >> 8) & 1;
    const int kf   = (idx >> 9) & 3;
    const int lt   = idx >> 11;
    const int l = lt * 32 + ln;
    const int k = kf * 16 + half * 8 + j;
    const float v = dw[(size_t)k * LL + l];
    const unsigned short hi = f2b(v);
    const unsigned short lo = f2b(v - b2f(hi));
    Wt[idx] = hi;
    Wt[262144 + idx] = lo;
}

// ---------------- Kernel 1: conv1d + BN + exp -> e_buf[b,t,f] + sumexp[b,f] ------
// (old k_sumexp + e store: conv computed ONCE for the whole pipeline now)
__global__ __launch_bounds__(256) void k_conv(
        const float* __restrict__ x, const float* __restrict__ cw,
        const float* __restrict__ cb, const float* __restrict__ gm,
        const float* __restrict__ bt, const float* __restrict__ mn,
        const float* __restrict__ vr, float* __restrict__ sumexp) {
    __shared__ __align__(16) float xsm[(64 + KW - 1) * CC];   // 592 floats
    __shared__ float red[4 * FF];
    const int tid = threadIdx.x;
    const int b  = blockIdx.x / (TT / 64);
    const int t0 = (blockIdx.x % (TT / 64)) * 64;
    const int f = tid & 63, ts = tid >> 6;

    float wreg[KW * CC];
#pragma unroll
    for (int kc = 0; kc < KW * CC; ++kc) wreg[kc] = cw[kc * FF + f];

    for (int i = tid; i < (64 + KW - 1) * CC; i += 256) {
        int row = i >> 3, c = i & 7;
        int t = t0 - (KW / 2) + row;
        xsm[i] = (t >= 0 && t < TT) ? x[((size_t)b * TT + t) * CC + c] : 0.0f;
    }
    const float s  = gm[f] * rsqrtf(vr[f] + 1e-3f);
    const float bb = bt[f] + (cb[f] - mn[f]) * s;
    const float s2 = s * L2E, b2 = bb * L2E;   // exp(z) = exp2(z*log2e)
    __syncthreads();

    float* eb = e_buf + ((size_t)b * TT + t0) * FF + f;
    const float4* xv = (const float4*)xsm;
    float esum = 0.f;
#pragma unroll 2
    for (int i = 0; i < 16; ++i) {
        const int tt = ts + 4 * i;
        float acc = 0.f;
#pragma unroll
        for (int k = 0; k < KW; ++k) {
            const float4 xa = xv[(tt + k) * 2];
            const float4 xb = xv[(tt + k) * 2 + 1];
            acc = fmaf(xa.x, wreg[k * 8 + 0], acc);
            acc = fmaf(xa.y, wreg[k * 8 + 1], acc);
            acc = fmaf(xa.z, wreg[k * 8 + 2], acc);
            acc = fmaf(xa.w, wreg[k * 8 + 3], acc);
            acc = fmaf(xb.x, wreg[k * 8 + 4], acc);
            acc = fmaf(xb.y, wreg[k * 8 + 5], acc);
            acc = fmaf(xb.z, wreg[k * 8 + 6], acc);
            acc = fmaf(xb.w, wreg[k * 8 + 7], acc);
        }
        float e = __builtin_amdgcn_exp2f(fmaf(acc, s2, b2));
        eb[tt * FF] = e;
        esum += e;
    }
    red[ts * FF + f] = esum;
    __syncthreads();
    if (ts == 0) {
        float tot = red[f] + red[FF + f] + red[2 * FF + f] + red[3 * FF + f];
        atomicAdd(&sumexp[b * FF + f], tot);
    }
}

// ---------------- Kernel 2: softmax+pos pack -> bf16 planes in LDS -> MFMA GEMM
// Conv phase REMOVED (reads e_buf). Waves de-phased in the lt loop; s_setprio
// around the MFMA cluster. PLAIN __launch_bounds__ — the min-waves arg clamps
// VGPR to 64 and spills hundreds of MB (measured R1/R4).
__global__ __launch_bounds__(512) void k_main(
        const float* __restrict__ gm,  const float* __restrict__ bt,
        const float* __restrict__ mn,  const float* __restrict__ vr,
        const unsigned short* __restrict__ Wt,
        const float* __restrict__ db,  const float* __restrict__ sumexp,
        float* __restrict__ shiftsum) {
    __shared__ __align__(16) unsigned short As[16384];   // 32 KB: hi | lo planes

    const int tid = threadIdx.x;
    const int b  = blockIdx.y;
    const int t0 = blockIdx.x * 128;
    const int f = tid & 63, tq = tid >> 6;   // tq in 0..7

    const float inv_se = 1.0f / sumexp[b * FF + f];
    const float tsf = exp2f(-0.20762050586796017f * (float)(f & ~1));
    const int kfh = ((f >> 4) << 1) | ((f >> 3) & 1);   // kf*2 + half
    const int jj  = f & 7;
    // pos encoding: ang(t) = t*tsf at t = t0+tq+8*i.
    // One precise sincos, then rotate by dA = 8*tsf per step (drift ~2e-6).
    const float ang0 = (float)(t0 + tq) * tsf;
    const float dA = 8.0f * tsf;
    float sv = sinf(ang0), cv = cosf(ang0);
    const float sd = sinf(dA), cd = cosf(dA);

    // phase A: softmax-normalize + pos -> split hi/lo -> As (16 t per thread)
    const float* eb = e_buf + ((size_t)b * TT + t0) * FF + f;
#pragma unroll 4
    for (int i = 0; i < 16; ++i) {
        const int tt = tq + 8 * i;
        float ev = eb[tt * FF];
        float p = (f & 1) ? cv : sv;
        float h = fmaf(ev, inv_se, p);
        const unsigned short hi = f2b(h);
        const unsigned short lo = f2b(h - b2f(hi));
        const int off = ((tt >> 5) * 8 + kfh) * 256 + (tt & 31) * 8 + jj;
        As[off] = hi;
        As[8192 + off] = lo;
        float ns = fmaf(sv, cd, cv * sd);
        float nc = fmaf(cv, cd, -(sv * sd));
        sv = ns; cv = nc;
    }
    __syncthreads();

    // ---- main loop: de-phased waves, no barriers ----
    const int lane = tid & 63;
    const int wv   = tid >> 6;            // 0..7
    const int half = lane >> 5;
    const int ln31 = lane & 31;
    const int vbase = (half << 9) | (ln31 << 4);            // byte offset of lane
    const char* Ab = (const char*)As;
    const char* Wb = (const char*)Wt;

#pragma unroll 1
    for (int i = 0; i < 16; ++i) {
        const int lt = (i + 2 * wv) & 15;   // de-phase: waves start at different lt
        const int ltile = lt * 8 + wv;      // coverage per wave unchanged (bijective)
        const int lbase = ltile * 32;
        const char* wp = Wb + ((size_t)ltile << 12) + vbase;
        short8 Whi[4], Wlo[4];
#pragma unroll
        for (int kf = 0; kf < 4; ++kf) {
            Whi[kf] = *reinterpret_cast<const short8*>(wp + kf * 1024);
            Wlo[kf] = *reinterpret_cast<const short8*>(wp + 524288 + kf * 1024);
        }
        const float dbn = db[lbase + ln31] * (-L2E);   // exp(-z) = exp2(-z*log2e)

        float ss[4] = {0.f, 0.f, 0.f, 0.f};
#pragma unroll
        for (int nt = 0; nt < 4; ++nt) {
            floatx16 acc = {0.f, 0.f, 0.f, 0.f, 0.f, 0.f, 0.f, 0.f,
                            0.f, 0.f, 0.f, 0.f, 0.f, 0.f, 0.f, 0.f};
            __builtin_amdgcn_s_setprio(1);
#pragma unroll
            for (int kf = 0; kf < 4; ++kf) {
                const int ao = (nt * 8 + kf * 2) << 9;
                short8 Ahi = *reinterpret_cast<const short8*>(Ab + ao + vbase);
                short8 Alo = *reinterpret_cast<const short8*>(Ab + 16384 + ao + vbase);
                acc = __builtin_amdgcn_mfma_f32_32x32x16_bf16(Ahi, Whi[kf], acc, 0, 0, 0);
                acc = __builtin_amdgcn_mfma_f32_32x32x16_bf16(Alo, Whi[kf], acc, 0, 0, 0);
                acc = __builtin_amdgcn_mfma_f32_32x32x16_bf16(Ahi, Wlo[kf], acc, 0, 0, 0);
            }
            __builtin_amdgcn_s_setprio(0);
            // sum of 16 sigmoids, 4-way reciprocal batching:
            // 1/a0+1/a1+1/a2+1/a3 = ((a0+a1)*a2*a3 + (a2+a3)*a0*a1) / (a0*a1*a2*a3)
#pragma unroll
            for (int q = 0; q < 4; ++q) {
                float e0 = __builtin_amdgcn_exp2f(fmaf(acc[4 * q + 0], -L2E, dbn));
                float e1 = __builtin_amdgcn_exp2f(fmaf(acc[4 * q + 1], -L2E, dbn));
                float e2 = __builtin_amdgcn_exp2f(fmaf(acc[4 * q + 2], -L2E, dbn));
                float e3 = __builtin_amdgcn_exp2f(fmaf(acc[4 * q + 3], -L2E, dbn));
                float a0 = 1.f + e0, a1 = 1.f + e1, a2 = 1.f + e2, a3 = 1.f + e3;
                float p01 = a0 * a1, p23 = a2 * a3;
                float num = fmaf(a0 + a1, p23, (a2 + a3) * p01);
                ss[q] = fmaf(num, __builtin_amdgcn_rcpf(p01 * p23), ss[q]);
            }
        }
        float ssum = (ss[0] + ss[1]) + (ss[2] + ss[3]);
        ssum += __shfl_xor(ssum, 32);
        if (half == 0)
            atomicAdd(shiftsum + (size_t)b * LL + lbase + ln31, ssum);
    }
}

// ---------------- Kernel 3: truncated Gaussian warp (shift = 2*S - T) -------------
__global__ __launch_bounds__(256) void k_warp(
        const float* __restrict__ shiftsum, const float* __restrict__ x,
        float* __restrict__ out) {
    const int idx = blockIdx.x * 256 + threadIdx.x;  // = b*L + l
    const int l = idx & (LL - 1);
    const int b = idx >> 12;
    const float sh = fmaf(2.0f, shiftsum[idx], -(float)TT);
    const float scale = (float)TT / (float)LL;
    const float center = ((float)(l + 1) + sh) * scale;
    const float R = 7.0f;
    int tlo = (int)ceilf(center - 1.0f - R);
    int thi = (int)floorf(center - 1.0f + R);
    if (tlo < 0) tlo = 0;
    if (thi > TT - 1) thi = TT - 1;
    float acc[CC];
#pragma unroll
    for (int c = 0; c < CC; ++c) acc[c] = 0.f;
    const float inv_amp = (float)(1.0 / 1.772637204826652);
    for (int t = tlo; t <= thi; ++t) {
        float d = (float)(t + 1) - center;
        float w = __expf(-d * d) * inv_amp;   // WIDTH = 1
        const float4 x0 = *reinterpret_cast<const float4*>(x + ((size_t)b * TT + t) * CC);
        const float4 x1 = *reinterpret_cast<const float4*>(x + ((size_t)b * TT + t) * CC + 4);
        acc[0] = fmaf(w, x0.x, acc[0]);
        acc[1] = fmaf(w, x0.y, acc[1]);
        acc[2] = fmaf(w, x0.z, acc[2]);
        acc[3] = fmaf(w, x0.w, acc[3]);
        acc[4] = fmaf(w, x1.x, acc[4]);
        acc[5] = fmaf(w, x1.y, acc[5]);
        acc[6] = fmaf(w, x1.z, acc[6]);
        acc[7] = fmaf(w, x1.w, acc[7]);
    }
    float* o = out + (size_t)idx * CC;
    *reinterpret_cast<float4*>(o)     = make_float4(acc[0], acc[1], acc[2], acc[3]);
    *reinterpret_cast<float4*>(o + 4) = make_float4(acc[4], acc[5], acc[6], acc[7]);
}

extern "C" void kernel_launch(void* const* d_in, const int* in_sizes, int n_in,
                              void* d_out, int out_size, void* d_ws, size_t ws_size,
                              hipStream_t stream) {
    const float* x  = (const float*)d_in[0];
    const float* cw = (const float*)d_in[1];
    const float* cb = (const float*)d_in[2];
    const float* gm = (const float*)d_in[3];
    const float* bt = (const float*)d_in[4];
    const float* mn = (const float*)d_in[5];
    const float* vr = (const float*)d_in[6];
    const float* dw = (const float*)d_in[7];
    const float* db = (const float*)d_in[8];

    float* sumexp      = (float*)d_ws;                        // 1024 floats
    float* shiftsum    = sumexp + BB * FF;                    // 65536 floats
    unsigned short* Wt = (unsigned short*)(shiftsum + BB * LL); // 524288 ushorts (1 MB)

    hipMemsetAsync(sumexp, 0, (size_t)(BB * FF + BB * LL) * sizeof(float), stream);

    k_split<<<(FF * LL) / 256, 256, 0, stream>>>(dw, Wt);
    k_conv<<<BB * (TT / 64), 256, 0, stream>>>(x, cw, cb, gm, bt, mn, vr, sumexp);
    k_main<<<dim3(TT / 128, BB), 512, 0, stream>>>(gm, bt, mn, vr,
                                                   Wt, db, sumexp, shiftsum);
    k_warp<<<(BB * LL) / 256, 256, 0, stream>>>(shiftsum, x, (float*)d_out);
}